// Round 16
// baseline (751.130 us; speedup 1.0000x reference)
//
#include <hip/hip_runtime.h>
#include <hip/hip_bf16.h>

#define LRELU_ALPHA 0.3f
#define LN_EPS 1e-3f
#define G 768          // persistent grid: 3 blocks/CU x 256 CUs (co-resident by construction)
#define DIV_TI 8
#define DIV_JC 4

typedef short bf16x8 __attribute__((ext_vector_type(8)));
typedef float f32x4 __attribute__((ext_vector_type(4)));

static __device__ __forceinline__ unsigned short f2bf(float f) {
    union { float f; unsigned u; } v; v.f = f;
    unsigned r = v.u + 0x7fffu + ((v.u >> 16) & 1u);  // RNE
    return (unsigned short)(r >> 16);
}

// async 16B global -> LDS (DMA). LDS dest = wave-uniform base + lane*16.
#define ASYNC_CP16(gsrc, ldst)                                                  \
    __builtin_amdgcn_global_load_lds(                                           \
        (const __attribute__((address_space(1))) unsigned int*)(gsrc),          \
        (__attribute__((address_space(3))) unsigned int*)(ldst), 16, 0, 0)

// Grid-wide barrier: single-use counter per barrier (memset 0 before launch).
static __device__ __forceinline__ void grid_barrier(unsigned* c) {
    __syncthreads();
    if (threadIdx.x == 0) {
        __threadfence();
        atomicAdd(c, 1u);
        while (atomicAdd(c, 0u) < (unsigned)G) __builtin_amdgcn_s_sleep(8);
        __threadfence();
    }
    __syncthreads();
}

// ---------------------------------------------------------------------------
// GEMM phase: [h | t] = A[M,lda]bf16 @ (BT[1152,ldb]bf16)^T + be
// 64x64 tiles (r12 inner loop), 1152 tiles looped over G blocks.
// ---------------------------------------------------------------------------
static __device__ __forceinline__
void gemm_phase(const unsigned short* __restrict__ A, int lda,
                const unsigned short* __restrict__ BT, int ldb,
                const float* __restrict__ bias,
                float* __restrict__ C, float* __restrict__ t,
                int K, unsigned char* smem) {
    unsigned short* As = (unsigned short*)smem;     // 64x32
    unsigned short* Bs = As + 64 * 32;              // 64x32 (8 KB total)
    const int tid = threadIdx.x;
    const int w = tid >> 6, lane = tid & 63;
    const int q = lane >> 4, m16 = lane & 15;
    const int wr = (w >> 1) * 32, wc = (w & 1) * 32;
    const int sr = tid >> 2, sc = (tid & 3) * 8;
    unsigned short* lA0 = As + tid * 8;
    unsigned short* lB0 = Bs + tid * 8;

    for (int tileId = blockIdx.x; tileId < 18 * 64; tileId += G) {
        const int bx = tileId % 18, by = tileId / 18;
        const int br = by * 64, bc = bx * 64;
        const unsigned short* gA0 = A + (size_t)(br + sr) * lda + sc;
        const unsigned short* gB0 = BT + (size_t)(bc + sr) * ldb + sc;
        f32x4 acc[2][2] = {};
        for (int k0 = 0; k0 < K; k0 += 32) {
            __syncthreads();                      // protect prior LDS reads
            ASYNC_CP16(gA0 + k0, lA0);
            ASYNC_CP16(gB0 + k0, lB0);
            __syncthreads();                      // waits DMA (vmcnt drained)
            bf16x8 af[2], bfr[2];
#pragma unroll
            for (int i = 0; i < 2; ++i)
                af[i] = *(const bf16x8*)(As + (wr + 16 * i + m16) * 32 + q * 8);
#pragma unroll
            for (int j = 0; j < 2; ++j)
                bfr[j] = *(const bf16x8*)(Bs + (wc + 16 * j + m16) * 32 + q * 8);
#pragma unroll
            for (int i = 0; i < 2; ++i)
#pragma unroll
                for (int j = 0; j < 2; ++j)
                    acc[i][j] = __builtin_amdgcn_mfma_f32_16x16x32_bf16(af[i], bfr[j], acc[i][j], 0, 0, 0);
        }
#pragma unroll
        for (int i = 0; i < 2; ++i) {
            const int gr = br + wr + 16 * i + q * 4;
#pragma unroll
            for (int j = 0; j < 2; ++j) {
                const int gc = bc + wc + 16 * j + m16;
                if (gc < 1024) {
                    const float b = bias[gc];
#pragma unroll
                    for (int r = 0; r < 4; ++r)
                        C[(size_t)(gr + r) * 1024 + gc] = acc[i][j][r] + b;
                } else if (gc < 1039) {
                    const float b = bias[gc];
#pragma unroll
                    for (int r = 0; r < 4; ++r)
                        t[(size_t)(gr + r) * 15 + (gc - 1024)] = acc[i][j][r] + b;
                }
            }
        }
    }
}

// ---------------------------------------------------------------------------
// Diversity phase: 2048 work units (512 i-tiles x 4 j-chunks) over G blocks.
// 2 i-rows/wave, flat 15-float LDS rows (0 conflicts).
// ---------------------------------------------------------------------------
static __device__ __forceinline__
void div_phase(const float* __restrict__ t, float* __restrict__ dvp,
               unsigned char* smem, int N) {
    float* tj_s = (float*)smem;                   // 256*15 floats = 15360 B
    const int tid = threadIdx.x;
    const int lane = tid & 63, g = tid >> 6;
    for (int u = blockIdx.x; u < (N / DIV_TI) * DIV_JC; u += G) {
        const int bx = u & 511, jc = u >> 9;
        const int i0 = bx * DIV_TI + g * 2;
        const int jbeg = jc * (N / DIV_JC), jend = jbeg + N / DIV_JC;
        float ti[2][15];
#pragma unroll
        for (int r = 0; r < 2; ++r)
#pragma unroll
            for (int d = 0; d < 15; ++d)
                ti[r][d] = t[(i0 + r) * 15 + d];
        float acc[2][5] = {};
        for (int j0 = jbeg; j0 < jend; j0 += 256) {
            __syncthreads();
#pragma unroll
            for (int it = 0; it < 15; ++it)
                tj_s[it * 256 + tid] = t[j0 * 15 + it * 256 + tid];
            __syncthreads();
#pragma unroll
            for (int m = 0; m < 4; ++m) {
                const float* rp = tj_s + (m * 64 + lane) * 15;
#pragma unroll
                for (int r = 0; r < 2; ++r)
#pragma unroll
                    for (int k = 0; k < 5; ++k) {
                        const float s = fabsf(ti[r][3 * k]     - rp[3 * k])
                                      + fabsf(ti[r][3 * k + 1] - rp[3 * k + 1])
                                      + fabsf(ti[r][3 * k + 2] - rp[3 * k + 2]);
                        acc[r][k] += __expf(-s);
                    }
            }
        }
#pragma unroll
        for (int r = 0; r < 2; ++r)
#pragma unroll
            for (int k = 0; k < 5; ++k)
#pragma unroll
                for (int off = 32; off > 0; off >>= 1)
                    acc[r][k] += __shfl_xor(acc[r][k], off, 64);
        if (lane == 0) {
            float* dst = dvp + (size_t)jc * N * 5;
#pragma unroll
            for (int r = 0; r < 2; ++r)
#pragma unroll
                for (int k = 0; k < 5; ++k)
                    dst[(i0 + r) * 5 + k] = acc[r][k];
        }
    }
}

// ---------------------------------------------------------------------------
// LN phases (mid: -> bf16 hc; head: fused wf dot -> out). Row loop over G.
// ---------------------------------------------------------------------------
static __device__ __forceinline__
void ln_mid_phase(const float* __restrict__ h, const float* __restrict__ dvp,
                  const float* __restrict__ beta, unsigned short* __restrict__ hc_bf,
                  unsigned char* smem, int M) {
    float* red = (float*)smem;
    const int tid = threadIdx.x;
    const int lane = tid & 63, wave = tid >> 6;
    for (int i = blockIdx.x; i < M; i += G) {
        __syncthreads();
        float v[5];
        float s = 0.f, s2 = 0.f;
#pragma unroll
        for (int r = 0; r < 5; ++r) {
            const int c = tid + r * 256;
            if (c < 1029) {
                float xv;
                if (c < 1024) {
                    xv = h[(size_t)i * 1024 + c];
                } else {
                    const int k = c - 1024;
                    xv = 0.f;
#pragma unroll
                    for (int jc = 0; jc < DIV_JC; ++jc)
                        xv += dvp[(size_t)jc * M * 5 + i * 5 + k];
                }
                v[r] = xv; s += xv; s2 += xv * xv;
            }
        }
#pragma unroll
        for (int off = 32; off > 0; off >>= 1) {
            s += __shfl_down(s, off, 64);
            s2 += __shfl_down(s2, off, 64);
        }
        if (lane == 0) { red[wave] = s; red[4 + wave] = s2; }
        __syncthreads();
        const float S = red[0] + red[1] + red[2] + red[3];
        const float S2 = red[4] + red[5] + red[6] + red[7];
        const float mu = S / 1029.f;
        const float var = S2 / 1029.f - mu * mu;
        const float rstd = rsqrtf(var + LN_EPS);
#pragma unroll
        for (int r = 0; r < 5; ++r) {
            const int c = tid + r * 256;
            if (c < 1029) {
                float y = (v[r] - mu) * rstd + beta[c];
                y = (y >= 0.f) ? y : LRELU_ALPHA * y;
                hc_bf[(size_t)i * 1056 + c] = f2bf(y);
            } else if (c < 1056) {
                hc_bf[(size_t)i * 1056 + c] = 0;
            }
        }
    }
}

static __device__ __forceinline__
void head_phase(const float* __restrict__ h, const float* __restrict__ dvp,
                const float* __restrict__ beta, const float* __restrict__ wf,
                const float* __restrict__ bfp, float* __restrict__ out,
                unsigned char* smem, int M) {
    float* red = (float*)smem;
    const int tid = threadIdx.x;
    const int lane = tid & 63, wave = tid >> 6;
    for (int i = blockIdx.x; i < M; i += G) {
        __syncthreads();
        float v[5];
        float s = 0.f, s2 = 0.f;
#pragma unroll
        for (int r = 0; r < 5; ++r) {
            const int c = tid + r * 256;
            if (c < 1029) {
                float xv;
                if (c < 1024) {
                    xv = h[(size_t)i * 1024 + c];
                } else {
                    const int k = c - 1024;
                    xv = 0.f;
#pragma unroll
                    for (int jc = 0; jc < DIV_JC; ++jc)
                        xv += dvp[(size_t)jc * M * 5 + i * 5 + k];
                }
                v[r] = xv; s += xv; s2 += xv * xv;
            }
        }
#pragma unroll
        for (int off = 32; off > 0; off >>= 1) {
            s += __shfl_down(s, off, 64);
            s2 += __shfl_down(s2, off, 64);
        }
        if (lane == 0) { red[wave] = s; red[4 + wave] = s2; }
        __syncthreads();
        const float S = red[0] + red[1] + red[2] + red[3];
        const float S2 = red[4] + red[5] + red[6] + red[7];
        const float mu = S / 1029.f;
        const float var = S2 / 1029.f - mu * mu;
        const float rstd = rsqrtf(var + LN_EPS);
        float hsum = 0.f;
#pragma unroll
        for (int r = 0; r < 5; ++r) {
            const int c = tid + r * 256;
            if (c < 1029) {
                float y = (v[r] - mu) * rstd + beta[c];
                y = (y >= 0.f) ? y : LRELU_ALPHA * y;
                hsum += y * wf[c];
            }
        }
#pragma unroll
        for (int off = 32; off > 0; off >>= 1) hsum += __shfl_down(hsum, off, 64);
        if (lane == 0) red[8 + wave] = hsum;
        __syncthreads();
        if (tid == 0) out[i] = red[8] + red[9] + red[10] + red[11] + bfp[0];
    }
}

// ---------------------------------------------------------------------------
// Persistent fused kernel. KEY FIX vs r13: amdgpu_waves_per_eu(3,3).
// r13 used __launch_bounds__(256,3) = MIN waves only -> allocator targeted
// 8 waves/EU, pinned 64 VGPRs, spilled every phase (50 MB scratch, 3.3x).
// With max=3 the allocator has no incentive below 170 regs; all phases'
// ~110 live regs fit spill-free. 3 blocks/CU x 256 CU = 768 co-resident.
// ---------------------------------------------------------------------------
__global__ __attribute__((amdgpu_flat_work_group_size(256, 256), amdgpu_waves_per_eu(3, 3)))
void fused_all(const float* __restrict__ x,
               const float* __restrict__ w0a, const float* __restrict__ b0a,
               const float* __restrict__ w0b, const float* __restrict__ b0b,
               const float* __restrict__ beta0,
               const float* __restrict__ w1a, const float* __restrict__ b1a,
               const float* __restrict__ w1b, const float* __restrict__ b1b,
               const float* __restrict__ beta1,
               const float* __restrict__ wf, const float* __restrict__ bfp,
               float* __restrict__ out, unsigned* __restrict__ cnt,
               float* __restrict__ h, float* __restrict__ t,
               float* __restrict__ dvp,
               float* __restrict__ be0, float* __restrict__ be1,
               unsigned short* __restrict__ x_bf,
               unsigned short* __restrict__ hc_bf,
               unsigned short* __restrict__ bT0,
               unsigned short* __restrict__ bT1) {
    __shared__ __align__(16) unsigned char smem[15360];
    const int tid = threadIdx.x;
    const int lane = tid & 63, w = tid >> 6;

    // ---------------- P0: prep ----------------
    {
        float (*tile)[33] = (float(*)[33])smem;
        for (int wb = blockIdx.x; wb < 4011; wb += G) {
            if (wb < 2048) {                      // cast x -> x_bf
                const int i = (wb * 256 + tid) * 4;
                const float4 v = *(const float4*)(x + i);
                ushort4 o;
                o.x = f2bf(v.x); o.y = f2bf(v.y); o.z = f2bf(v.z); o.w = f2bf(v.w);
                *(ushort4*)(x_bf + i) = o;
            } else if (wb < 3616) {               // transpose w0a / w1a
                const int isB1 = (wb >= 2560);
                const int b2 = wb - (isB1 ? 2560 : 2048);
                const int nb = (b2 & 31) * 32, kb = (b2 >> 5) * 32;
                const int tx = tid & 31, ty = tid >> 5;
                const float* W = isB1 ? w1a : w0a;
                const int Kmax = isB1 ? 1029 : 512;
#pragma unroll
                for (int i = 0; i < 4; ++i) {
                    const int k = kb + ty + i * 8;
                    tile[ty + i * 8][tx] = (k < Kmax) ? W[(size_t)k * 1024 + nb + tx] : 0.f;
                }
                __syncthreads();
#pragma unroll
                for (int i = 0; i < 4; ++i) {
                    if (isB1) bT1[(size_t)(nb + ty + i * 8) * 1056 + kb + tx] = f2bf(tile[tx][ty + i * 8]);
                    else      bT0[(size_t)(nb + ty + i * 8) * 512  + kb + tx] = f2bf(tile[tx][ty + i * 8]);
                }
                __syncthreads();
            } else if (wb < 4003) {               // wcomb 0/1
                const int is1 = (wb >= 3745);
                const int b4 = wb - (is1 ? 3745 : 3616);
                const int row = b4 * 4 + w;
                const int F = is1 ? 1029 : 512;
                if (row <= F) {
                    const float* wa = is1 ? w1a : w0a;
                    const float* ba = is1 ? b1a : b0a;
                    const float* wbp = is1 ? w1b : w0b;
                    const float* bbp = is1 ? b1b : b0b;
                    const float* src = (row < F) ? (wa + (size_t)row * 1024) : ba;
                    float acc[15] = {};
                    for (int hh = lane; hh < 1024; hh += 64) {
                        const float a = src[hh];
                        const float* wr = wbp + hh * 15;
#pragma unroll
                        for (int c = 0; c < 15; ++c) acc[c] += a * wr[c];
                    }
#pragma unroll
                    for (int c = 0; c < 15; ++c)
#pragma unroll
                        for (int off = 32; off > 0; off >>= 1)
                            acc[c] += __shfl_xor(acc[c], off, 64);
                    if (lane < 15) {
                        if (row < F) {
                            if (is1) bT1[(size_t)(1024 + lane) * 1056 + row] = f2bf(acc[lane]);
                            else     bT0[(size_t)(1024 + lane) * 512  + row] = f2bf(acc[lane]);
                        } else {
                            if (is1) be1[1024 + lane] = acc[lane] + bbp[lane];
                            else     be0[1024 + lane] = acc[lane] + bbp[lane];
                        }
                    }
                }
            } else {                              // bias copies
                const int b6 = wb - 4003;
                if (b6 < 4) be0[b6 * 256 + tid] = b0a[b6 * 256 + tid];
                else        be1[(b6 - 4) * 256 + tid] = b1a[(b6 - 4) * 256 + tid];
            }
        }
    }
    grid_barrier(cnt + 0);
    gemm_phase(x_bf, 512, bT0, 512, be0, h, t, 512, smem);
    grid_barrier(cnt + 1);
    div_phase(t, dvp, smem, 4096);
    grid_barrier(cnt + 2);
    ln_mid_phase(h, dvp, beta0, hc_bf, smem, 4096);
    grid_barrier(cnt + 3);
    gemm_phase(hc_bf, 1056, bT1, 1056, be1, h, t, 1056, smem);
    grid_barrier(cnt + 4);
    div_phase(t, dvp, smem, 4096);
    grid_barrier(cnt + 5);
    head_phase(h, dvp, beta1, wf, bfp, out, smem, 4096);
}

extern "C" void kernel_launch(void* const* d_in, const int* in_sizes, int n_in,
                              void* d_out, int out_size, void* d_ws, size_t ws_size,
                              hipStream_t stream) {
    const float* x     = (const float*)d_in[0];
    const float* w0a   = (const float*)d_in[1];
    const float* b0a   = (const float*)d_in[2];
    const float* w0b   = (const float*)d_in[3];
    const float* b0b   = (const float*)d_in[4];
    const float* beta0 = (const float*)d_in[5];
    const float* w1a   = (const float*)d_in[6];
    const float* b1a   = (const float*)d_in[7];
    const float* w1b   = (const float*)d_in[8];
    const float* b1b   = (const float*)d_in[9];
    const float* beta1 = (const float*)d_in[10];
    const float* wf    = (const float*)d_in[11];
    const float* bf    = (const float*)d_in[12];
    float* out = (float*)d_out;

    const int M = 4096, NF = 512, CP = 1056;

    unsigned* cnt = (unsigned*)d_ws;                // barrier counters (256 B)
    float* h   = (float*)((char*)d_ws + 256);       // 4096 x 1024
    float* t   = h   + (size_t)M * 1024;            // 4096 x 15
    float* dvp = t   + (size_t)M * 15;              // 4 x 4096 x 5
    float* be0 = dvp + (size_t)DIV_JC * M * 5;      // 1152
    float* be1 = be0 + 1152;                        // 1152
    unsigned short* x_bf  = (unsigned short*)(be1 + 1152);   // 4096 x 512
    unsigned short* hc_bf = x_bf + (size_t)M * NF;           // 4096 x 1056
    unsigned short* bT0   = hc_bf + (size_t)M * CP;          // 1152 x 512
    unsigned short* bT1   = bT0 + (size_t)1152 * NF;         // 1152 x 1056

    hipMemsetAsync(d_ws, 0, 256, stream);
    fused_all<<<G, 256, 0, stream>>>(x, w0a, b0a, w0b, b0b, beta0,
                                     w1a, b1a, w1b, b1b, beta1, wf, bf,
                                     out, cnt, h, t, dvp, be0, be1,
                                     x_bf, hc_bf, bT0, bT1);
}